// Round 1
// baseline (64.625 us; speedup 1.0000x reference)
//
#include <hip/hip_runtime.h>

// Problem: N=8 prior blocks, B=4, C=256, H=W=64.
// V = concat(blocks, x) -> [9,4,256,64,64]
// GroupNorm(1 group) over (C,H,W) per (n,b); logits = <w, K> over c;
// softmax over n; out = sum_n attn * V.
//
// Key identity: logits = rstd*(S - mean*sum_wg) + sum_wgb
//   where S[n,b,hw] = sum_c (w[c]*gnw[c]) * V[n,b,c,hw]
//         sum_wg = sum_c w[c]*gnw[c],  sum_wgb = sum_c w[c]*gnb[c]

#define NPRI 8
#define N1   9
#define BB   4
#define CC   256
#define HWN  4096
#define CHW  (CC * HWN)          // 1048576
#define NB   (N1 * BB)           // 36
#define GN_EPS 1e-5f

// workspace layout (floats):
//   [0..35]      sum per (n,b)
//   [36..71]     sumsq per (n,b)
//   [128 ..)     S_part[4][36][4096]  = 589824 floats
//   [589952 ..)  attn[9][4][4096]     = 147456 floats
#define WS_SUM    0
#define WS_SQ     36
#define WS_SPART  128
#define WS_ATTN   589952

// ---------------- kernel 1: stats + channel-dot partials ----------------
// grid = 36 (n,b) * 4 (c-quarter) * 4 (hw-quarter) = 576 blocks, 256 thr
__global__ __launch_bounds__(256) void k1_stats(
        const float* __restrict__ blocks, const float* __restrict__ x,
        const float* __restrict__ w, const float* __restrict__ gnw,
        float* __restrict__ ws) {
    const int bid = blockIdx.x;
    const int nb  = bid >> 4;        // 0..35
    const int rem = bid & 15;
    const int cq  = rem >> 2;        // 0..3
    const int hwq = rem & 3;         // 0..3
    const int t   = threadIdx.x;

    const float* base = (nb < NPRI * BB)
        ? blocks + (size_t)nb * CHW
        : x + (size_t)(nb - NPRI * BB) * CHW;

    const int hw0 = hwq * 1024 + t * 4;
    float s0 = 0.f, s1 = 0.f, s2 = 0.f, s3 = 0.f;   // channel-dot partial
    float sum = 0.f, sq = 0.f;
    const int c0 = cq * 64;

    #pragma unroll 8
    for (int c = c0; c < c0 + 64; ++c) {
        const float4 v = *reinterpret_cast<const float4*>(base + (size_t)c * HWN + hw0);
        const float wg = w[c] * gnw[c];
        sum += v.x + v.y + v.z + v.w;
        sq  += v.x * v.x + v.y * v.y + v.z * v.z + v.w * v.w;
        s0 += wg * v.x; s1 += wg * v.y; s2 += wg * v.z; s3 += wg * v.w;
    }

    // write S partial (coalesced float4)
    float* Sp = ws + WS_SPART;
    *reinterpret_cast<float4*>(Sp + (size_t)(cq * NB + nb) * HWN + hw0) =
        make_float4(s0, s1, s2, s3);

    // block-reduce sum/sq -> atomicAdd
    #pragma unroll
    for (int off = 32; off; off >>= 1) {
        sum += __shfl_down(sum, off);
        sq  += __shfl_down(sq, off);
    }
    __shared__ float red[8];
    const int wave = t >> 6, lane = t & 63;
    if (lane == 0) { red[wave] = sum; red[4 + wave] = sq; }
    __syncthreads();
    if (t == 0) {
        const float S = red[0] + red[1] + red[2] + red[3];
        const float Q = red[4] + red[5] + red[6] + red[7];
        atomicAdd(ws + WS_SUM + nb, S);
        atomicAdd(ws + WS_SQ + nb, Q);
    }
}

// ---------------- kernel 2: finalize stats, softmax -> attn ----------------
// grid = B*HW/256 = 64 blocks, 256 threads
__global__ __launch_bounds__(256) void k2_attn(
        const float* __restrict__ w, const float* __restrict__ gnw,
        const float* __restrict__ gnb, float* __restrict__ ws) {
    const int t = threadIdx.x;

    // reduce sum_wg = <w,gnw>, sum_wgb = <w,gnb> across the block (C==256)
    float p = w[t] * gnw[t];
    float q = w[t] * gnb[t];
    #pragma unroll
    for (int off = 32; off; off >>= 1) {
        p += __shfl_down(p, off);
        q += __shfl_down(q, off);
    }
    __shared__ float red[8];
    __shared__ float swg_s, swgb_s;
    const int wave = t >> 6, lane = t & 63;
    if (lane == 0) { red[wave] = p; red[4 + wave] = q; }
    __syncthreads();
    if (t == 0) {
        swg_s  = red[0] + red[1] + red[2] + red[3];
        swgb_s = red[4] + red[5] + red[6] + red[7];
    }
    __syncthreads();
    const float swg = swg_s, swgb = swgb_s;

    const int idx = blockIdx.x * 256 + t;   // 0 .. 16384
    const int b  = idx >> 12;
    const int hw = idx & 4095;

    const float* Sp = ws + WS_SPART;
    float* attn = ws + WS_ATTN;

    float logit[N1];
    float mx = -1e30f;
    #pragma unroll
    for (int n = 0; n < N1; ++n) {
        const int nb = n * BB + b;
        const size_t o = (size_t)nb * HWN + hw;
        const float S = Sp[o] + Sp[(size_t)NB * HWN + o]
                      + Sp[(size_t)2 * NB * HWN + o] + Sp[(size_t)3 * NB * HWN + o];
        const float sum = ws[WS_SUM + nb];
        const float sq  = ws[WS_SQ + nb];
        const float mean = sum * (1.0f / CHW);
        const float var  = sq * (1.0f / CHW) - mean * mean;
        const float rstd = rsqrtf(var + GN_EPS);
        const float l = rstd * (S - mean * swg) + swgb;
        logit[n] = l;
        mx = fmaxf(mx, l);
    }
    float denom = 0.f;
    #pragma unroll
    for (int n = 0; n < N1; ++n) {
        const float e = __expf(logit[n] - mx);
        logit[n] = e;
        denom += e;
    }
    const float inv = 1.0f / denom;
    #pragma unroll
    for (int n = 0; n < N1; ++n)
        attn[(size_t)(n * BB + b) * HWN + hw] = logit[n] * inv;
}

// ---------------- kernel 3: out = sum_n attn * V ----------------
// grid = B*C*HW/1024 = 4096 blocks, 256 threads, float4/thread
__global__ __launch_bounds__(256) void k3_out(
        const float* __restrict__ blocks, const float* __restrict__ x,
        const float* __restrict__ ws, float* __restrict__ out) {
    const int bid = blockIdx.x;
    const int hwq = bid & 3;
    const int c   = (bid >> 2) & (CC - 1);
    const int b   = bid >> 10;
    const int t   = threadIdx.x;
    const int hw0 = hwq * 1024 + t * 4;

    const float* attn = ws + WS_ATTN;
    float a0 = 0.f, a1 = 0.f, a2 = 0.f, a3 = 0.f;

    #pragma unroll
    for (int n = 0; n < N1; ++n) {
        const float* vbase = (n < NPRI)
            ? blocks + ((size_t)(n * BB + b) * CC + c) * HWN
            : x + ((size_t)b * CC + c) * HWN;
        const float4 v = *reinterpret_cast<const float4*>(vbase + hw0);
        const float4 a = *reinterpret_cast<const float4*>(
            attn + (size_t)(n * BB + b) * HWN + hw0);
        a0 += a.x * v.x; a1 += a.y * v.y; a2 += a.z * v.z; a3 += a.w * v.w;
    }
    *reinterpret_cast<float4*>(out + ((size_t)(b * CC + c)) * HWN + hw0) =
        make_float4(a0, a1, a2, a3);
}

extern "C" void kernel_launch(void* const* d_in, const int* in_sizes, int n_in,
                              void* d_out, int out_size, void* d_ws, size_t ws_size,
                              hipStream_t stream) {
    const float* blocks = (const float*)d_in[0];
    const float* x      = (const float*)d_in[1];
    const float* w      = (const float*)d_in[2];
    const float* gnw    = (const float*)d_in[3];
    const float* gnb    = (const float*)d_in[4];
    float* out = (float*)d_out;
    float* ws  = (float*)d_ws;

    // zero the 72 accumulator floats (harness does not re-poison between replays)
    hipMemsetAsync(ws, 0, 72 * sizeof(float), stream);

    hipLaunchKernelGGL(k1_stats, dim3(576), dim3(256), 0, stream, blocks, x, w, gnw, ws);
    hipLaunchKernelGGL(k2_attn, dim3(64), dim3(256), 0, stream, w, gnw, gnb, ws);
    hipLaunchKernelGGL(k3_out, dim3(4096), dim3(256), 0, stream, blocks, x, ws, out);
}

// Round 2
// 61.643 us; speedup vs baseline: 1.0484x; 1.0484x over previous
//
#include <hip/hip_runtime.h>

// Problem: N=8 prior blocks, B=4, C=256, H=W=64.
// V = concat(blocks, x) -> [9,4,256,64,64]
// GroupNorm(1 group) over (C,H,W) per (n,b); logits = <w, K> over c;
// softmax over n; out = sum_n attn * V.
//
// Key identity: logits = rstd*(S - mean*sum_wg) + sum_wgb
//   where S[n,b,hw] = sum_c (w[c]*gnw[c]) * V[n,b,c,hw]
//         sum_wg = sum_c w[c]*gnw[c],  sum_wgb = sum_c w[c]*gnb[c]

#define NPRI 8
#define N1   9
#define BB   4
#define CC   256
#define HWN  4096
#define CHW  (CC * HWN)          // 1048576
#define NB   (N1 * BB)           // 36
#define GN_EPS 1e-5f

// workspace layout (floats):
//   [0..1151]       psum[36][32]   per-(nb, cq*8+hwh) partial sum
//   [1152..2303]    psq [36][32]   partial sum-of-squares
//   [2304..)        S_part[4][36][4096] = 589824 floats (16B-aligned: 2304*4=9216)
//   [592128..)      attn[9][4][4096]    = 147456 floats
#define WS_PSUM   0
#define WS_PSQ    1152
#define WS_SPART  2304
#define WS_ATTN   592128

// ---------------- kernel 1: stats + channel-dot partials ----------------
// grid = 36 (nb) * 4 (cq) * 8 (hwh) = 1152 blocks, 256 threads.
// Block covers 64 channels x 512 hw. Threads split: t<128 -> lower 32 ch,
// t>=128 -> upper 32 ch, same hw lanes; channel-dot halves combined via LDS.
__global__ __launch_bounds__(256) void k1_stats(
        const float* __restrict__ blocks, const float* __restrict__ x,
        const float* __restrict__ w, const float* __restrict__ gnw,
        float* __restrict__ ws) {
    const int bid = blockIdx.x;
    const int nb  = bid >> 5;            // 0..35
    const int cq  = (bid >> 3) & 3;      // 0..3
    const int hwh = bid & 7;             // 0..7
    const int t   = threadIdx.x;
    const int half = t >> 7;             // 0 or 1
    const int tl   = t & 127;

    const float* base = (nb < NPRI * BB)
        ? blocks + (size_t)nb * CHW
        : x + (size_t)(nb - NPRI * BB) * CHW;

    const int hw0 = hwh * 512 + tl * 4;
    const int c0  = cq * 64 + half * 32;

    float s0 = 0.f, s1 = 0.f, s2 = 0.f, s3 = 0.f;   // channel-dot partial
    float sum = 0.f, sq = 0.f;

    #pragma unroll 8
    for (int c = c0; c < c0 + 32; ++c) {
        const float4 v = *reinterpret_cast<const float4*>(base + (size_t)c * HWN + hw0);
        const float wg = w[c] * gnw[c];
        sum += v.x + v.y + v.z + v.w;
        sq  += v.x * v.x + v.y * v.y + v.z * v.z + v.w * v.w;
        s0 += wg * v.x; s1 += wg * v.y; s2 += wg * v.z; s3 += wg * v.w;
    }

    // combine the two c-halves' channel-dot via LDS, write coalesced float4
    __shared__ float4 sbuf[128];
    if (half) sbuf[tl] = make_float4(s0, s1, s2, s3);
    __syncthreads();
    if (!half) {
        const float4 o = sbuf[tl];
        float* Sp = ws + WS_SPART;
        *reinterpret_cast<float4*>(Sp + (size_t)(cq * NB + nb) * HWN + hw0) =
            make_float4(s0 + o.x, s1 + o.y, s2 + o.z, s3 + o.w);
    }

    // block-reduce sum/sq -> unique slot (no atomics, no memset needed)
    #pragma unroll
    for (int off = 32; off; off >>= 1) {
        sum += __shfl_down(sum, off);
        sq  += __shfl_down(sq, off);
    }
    __shared__ float red[8];
    const int wave = t >> 6, lane = t & 63;
    if (lane == 0) { red[wave] = sum; red[4 + wave] = sq; }
    __syncthreads();
    if (t == 0) {
        const int slot = nb * 32 + (bid & 31);
        ws[WS_PSUM + slot] = red[0] + red[1] + red[2] + red[3];
        ws[WS_PSQ  + slot] = red[4] + red[5] + red[6] + red[7];
    }
}

// ---------------- kernel 2: finalize stats, softmax -> attn ----------------
// grid = B*HW/256 = 64 blocks, 256 threads
__global__ __launch_bounds__(256) void k2_attn(
        const float* __restrict__ w, const float* __restrict__ gnw,
        const float* __restrict__ gnb, float* __restrict__ ws) {
    const int t = threadIdx.x;

    __shared__ float red[8];
    __shared__ float swg_s, swgb_s;
    __shared__ float mean_s[NB], rstd_s[NB];

    // reduce sum_wg = <w,gnw>, sum_wgb = <w,gnb> across the block (C==256)
    float p = w[t] * gnw[t];
    float q = w[t] * gnb[t];
    #pragma unroll
    for (int off = 32; off; off >>= 1) {
        p += __shfl_down(p, off);
        q += __shfl_down(q, off);
    }
    const int wave = t >> 6, lane = t & 63;
    if (lane == 0) { red[wave] = p; red[4 + wave] = q; }

    // threads 0..35: reduce the 32 stat partials for one nb
    if (t < NB) {
        float s = 0.f, ss = 0.f;
        #pragma unroll 8
        for (int i = 0; i < 32; ++i) {
            s  += ws[WS_PSUM + t * 32 + i];
            ss += ws[WS_PSQ  + t * 32 + i];
        }
        const float mean = s * (1.0f / CHW);
        const float var  = ss * (1.0f / CHW) - mean * mean;
        mean_s[t] = mean;
        rstd_s[t] = rsqrtf(var + GN_EPS);
    }
    __syncthreads();
    if (t == 0) {
        swg_s  = red[0] + red[1] + red[2] + red[3];
        swgb_s = red[4] + red[5] + red[6] + red[7];
    }
    __syncthreads();
    const float swg = swg_s, swgb = swgb_s;

    const int idx = blockIdx.x * 256 + t;   // 0 .. 16383
    const int b  = idx >> 12;
    const int hw = idx & 4095;

    const float* Sp = ws + WS_SPART;
    float* attn = ws + WS_ATTN;

    float logit[N1];
    float mx = -1e30f;
    #pragma unroll
    for (int n = 0; n < N1; ++n) {
        const int nb = n * BB + b;
        const size_t o = (size_t)nb * HWN + hw;
        const float S = Sp[o] + Sp[(size_t)NB * HWN + o]
                      + Sp[(size_t)2 * NB * HWN + o] + Sp[(size_t)3 * NB * HWN + o];
        const float l = rstd_s[nb] * (S - mean_s[nb] * swg) + swgb;
        logit[n] = l;
        mx = fmaxf(mx, l);
    }
    float denom = 0.f;
    #pragma unroll
    for (int n = 0; n < N1; ++n) {
        const float e = __expf(logit[n] - mx);
        logit[n] = e;
        denom += e;
    }
    const float inv = 1.0f / denom;
    #pragma unroll
    for (int n = 0; n < N1; ++n)
        attn[(size_t)(n * BB + b) * HWN + hw] = logit[n] * inv;
}

// ---------------- kernel 3: out = sum_n attn * V ----------------
// grid = B*C*HW/1024 = 4096 blocks, 256 threads, float4/thread
__global__ __launch_bounds__(256) void k3_out(
        const float* __restrict__ blocks, const float* __restrict__ x,
        const float* __restrict__ ws, float* __restrict__ out) {
    const int bid = blockIdx.x;
    const int hwq = bid & 3;
    const int c   = (bid >> 2) & (CC - 1);
    const int b   = bid >> 10;
    const int t   = threadIdx.x;
    const int hw0 = hwq * 1024 + t * 4;

    const float* attn = ws + WS_ATTN;
    float a0 = 0.f, a1 = 0.f, a2 = 0.f, a3 = 0.f;

    #pragma unroll
    for (int n = 0; n < N1; ++n) {
        const float* vbase = (n < NPRI)
            ? blocks + ((size_t)(n * BB + b) * CC + c) * HWN
            : x + ((size_t)b * CC + c) * HWN;
        const float4 v = *reinterpret_cast<const float4*>(vbase + hw0);
        const float4 a = *reinterpret_cast<const float4*>(
            attn + (size_t)(n * BB + b) * HWN + hw0);
        a0 += a.x * v.x; a1 += a.y * v.y; a2 += a.z * v.z; a3 += a.w * v.w;
    }
    float* optr = out + ((size_t)(b * CC + c)) * HWN + hw0;
    __builtin_nontemporal_store(a0, optr + 0);
    __builtin_nontemporal_store(a1, optr + 1);
    __builtin_nontemporal_store(a2, optr + 2);
    __builtin_nontemporal_store(a3, optr + 3);
}

extern "C" void kernel_launch(void* const* d_in, const int* in_sizes, int n_in,
                              void* d_out, int out_size, void* d_ws, size_t ws_size,
                              hipStream_t stream) {
    const float* blocks = (const float*)d_in[0];
    const float* x      = (const float*)d_in[1];
    const float* w      = (const float*)d_in[2];
    const float* gnw    = (const float*)d_in[3];
    const float* gnb    = (const float*)d_in[4];
    float* out = (float*)d_out;
    float* ws  = (float*)d_ws;

    hipLaunchKernelGGL(k1_stats, dim3(1152), dim3(256), 0, stream, blocks, x, w, gnw, ws);
    hipLaunchKernelGGL(k2_attn, dim3(64), dim3(256), 0, stream, w, gnw, gnb, ws);
    hipLaunchKernelGGL(k3_out, dim3(4096), dim3(256), 0, stream, blocks, x, ws, out);
}

// Round 3
// 59.417 us; speedup vs baseline: 1.0877x; 1.0375x over previous
//
#include <hip/hip_runtime.h>

// Problem: N=8 prior blocks, B=4, C=256, H=W=64.
// V = concat(blocks, x) -> [9,4,256,64,64]
// GroupNorm(1 group) over (C,H,W) per (n,b); logits = <w, K> over c;
// softmax over n; out = sum_n attn * V.
//
// Key identity: logits = rstd*(S - mean*sum_wg) + sum_wgb
//   where S[n,b,hw] = sum_c (w[c]*gnw[c]) * V[n,b,c,hw]
//         sum_wg = sum_c w[c]*gnw[c],  sum_wgb = sum_c w[c]*gnb[c]

#define NPRI 8
#define N1   9
#define BB   4
#define CC   256
#define HWN  4096
#define CHW  (CC * HWN)          // 1048576
#define NB   (N1 * BB)           // 36
#define GN_EPS 1e-5f

// workspace layout (floats):
//   [0..2303]      psum[36][64]   per-(nb, cq*16+hwseg) partial sum
//   [2304..4607]   psq [36][64]   partial sum-of-squares
//   [4608..)       S_part[4][36][4096] = 589824 floats (4608*4 bytes, 16B-aligned)
//   [594432..)     attn[9][4][4096]    = 147456 floats (16B-aligned)
#define WS_PSUM   0
#define WS_PSQ    2304
#define WS_SPART  4608
#define WS_ATTN   594432

// ---------------- kernel 1: stats + channel-dot partials ----------------
// grid = 36 (nb) * 4 (cq) * 16 (hwseg) = 2304 blocks (9 per CU exactly),
// 256 threads = 4 c-groups (16 ch each) x 64 lanes (64 float4 = 256 floats).
__global__ __launch_bounds__(256, 4) void k1_stats(
        const float* __restrict__ blocks, const float* __restrict__ x,
        const float* __restrict__ w, const float* __restrict__ gnw,
        float* __restrict__ ws) {
    const int bid   = blockIdx.x;
    const int nb    = bid >> 6;          // 0..35
    const int rem   = bid & 63;
    const int cq    = rem >> 4;          // 0..3
    const int hwseg = rem & 15;          // 0..15
    const int t     = threadIdx.x;
    const int cg    = t >> 6;            // 0..3
    const int lane  = t & 63;

    const float* base = (nb < NPRI * BB)
        ? blocks + (size_t)nb * CHW
        : x + (size_t)(nb - NPRI * BB) * CHW;

    const int hw0 = hwseg * 256 + lane * 4;
    const int c0  = cq * 64 + cg * 16;

    float s0 = 0.f, s1 = 0.f, s2 = 0.f, s3 = 0.f;   // channel-dot partial
    float sum = 0.f, sq = 0.f;

    #pragma unroll 4
    for (int c = c0; c < c0 + 16; ++c) {
        const float4 v = *reinterpret_cast<const float4*>(base + (size_t)c * HWN + hw0);
        const float wg = w[c] * gnw[c];
        sum += v.x + v.y + v.z + v.w;
        sq  += v.x * v.x + v.y * v.y + v.z * v.z + v.w * v.w;
        s0 += wg * v.x; s1 += wg * v.y; s2 += wg * v.z; s3 += wg * v.w;
    }

    // combine 4 c-groups' channel-dot via LDS; cg0 writes final cq-partial
    __shared__ float4 sbuf[3][64];
    if (cg) sbuf[cg - 1][lane] = make_float4(s0, s1, s2, s3);
    __syncthreads();
    if (!cg) {
        #pragma unroll
        for (int g = 0; g < 3; ++g) {
            const float4 o = sbuf[g][lane];
            s0 += o.x; s1 += o.y; s2 += o.z; s3 += o.w;
        }
        float* Sp = ws + WS_SPART;
        *reinterpret_cast<float4*>(Sp + (size_t)(cq * NB + nb) * HWN + hw0) =
            make_float4(s0, s1, s2, s3);
    }

    // block-reduce sum/sq -> unique slot (no atomics)
    #pragma unroll
    for (int off = 32; off; off >>= 1) {
        sum += __shfl_down(sum, off);
        sq  += __shfl_down(sq, off);
    }
    __shared__ float red[8];
    if (lane == 0) { red[cg] = sum; red[4 + cg] = sq; }
    __syncthreads();
    if (t == 0) {
        const int slot = nb * 64 + rem;
        ws[WS_PSUM + slot] = red[0] + red[1] + red[2] + red[3];
        ws[WS_PSQ  + slot] = red[4] + red[5] + red[6] + red[7];
    }
}

// ---------------- kernel 2: finalize stats, softmax -> attn ----------------
// grid = B*HW/256 = 64 blocks, 256 threads
__global__ __launch_bounds__(256) void k2_attn(
        const float* __restrict__ w, const float* __restrict__ gnw,
        const float* __restrict__ gnb, float* __restrict__ ws) {
    const int t = threadIdx.x;

    __shared__ float red[8];
    __shared__ float swg_s, swgb_s;
    __shared__ float mean_s[NB], rstd_s[NB];

    // reduce sum_wg = <w,gnw>, sum_wgb = <w,gnb> across the block (C==256)
    float p = w[t] * gnw[t];
    float q = w[t] * gnb[t];
    #pragma unroll
    for (int off = 32; off; off >>= 1) {
        p += __shfl_down(p, off);
        q += __shfl_down(q, off);
    }
    const int wave = t >> 6, lane = t & 63;
    if (lane == 0) { red[wave] = p; red[4 + wave] = q; }

    // threads 0..35: reduce the 64 stat partials for one nb
    if (t < NB) {
        float s = 0.f, ss = 0.f;
        #pragma unroll 8
        for (int i = 0; i < 64; ++i) {
            s  += ws[WS_PSUM + t * 64 + i];
            ss += ws[WS_PSQ  + t * 64 + i];
        }
        const float mean = s * (1.0f / CHW);
        const float var  = ss * (1.0f / CHW) - mean * mean;
        mean_s[t] = mean;
        rstd_s[t] = rsqrtf(var + GN_EPS);
    }
    __syncthreads();
    if (t == 0) {
        swg_s  = red[0] + red[1] + red[2] + red[3];
        swgb_s = red[4] + red[5] + red[6] + red[7];
    }
    __syncthreads();
    const float swg = swg_s, swgb = swgb_s;

    const int idx = blockIdx.x * 256 + t;   // 0 .. 16383
    const int b  = idx >> 12;
    const int hw = idx & 4095;

    const float* Sp = ws + WS_SPART;
    float* attn = ws + WS_ATTN;

    float logit[N1];
    float mx = -1e30f;
    #pragma unroll
    for (int n = 0; n < N1; ++n) {
        const int nb = n * BB + b;
        const size_t o = (size_t)nb * HWN + hw;
        const float S = Sp[o] + Sp[(size_t)NB * HWN + o]
                      + Sp[(size_t)2 * NB * HWN + o] + Sp[(size_t)3 * NB * HWN + o];
        const float l = rstd_s[nb] * (S - mean_s[nb] * swg) + swgb;
        logit[n] = l;
        mx = fmaxf(mx, l);
    }
    float denom = 0.f;
    #pragma unroll
    for (int n = 0; n < N1; ++n) {
        const float e = __expf(logit[n] - mx);
        logit[n] = e;
        denom += e;
    }
    const float inv = 1.0f / denom;
    #pragma unroll
    for (int n = 0; n < N1; ++n)
        attn[(size_t)(n * BB + b) * HWN + hw] = logit[n] * inv;
}

// ---------------- kernel 3: out = sum_n attn * V ----------------
// grid = B*C*HW/1024 = 4096 blocks (16 per CU exactly), 256 threads, float4/thread
__global__ __launch_bounds__(256) void k3_out(
        const float* __restrict__ blocks, const float* __restrict__ x,
        const float* __restrict__ ws, float* __restrict__ out) {
    const int bid = blockIdx.x;
    const int hwq = bid & 3;
    const int c   = (bid >> 2) & (CC - 1);
    const int b   = bid >> 10;
    const int t   = threadIdx.x;
    const int hw0 = hwq * 1024 + t * 4;

    const float* attn = ws + WS_ATTN;
    float a0 = 0.f, a1 = 0.f, a2 = 0.f, a3 = 0.f;

    #pragma unroll
    for (int n = 0; n < N1; ++n) {
        const float* vbase = (n < NPRI)
            ? blocks + ((size_t)(n * BB + b) * CC + c) * HWN
            : x + ((size_t)b * CC + c) * HWN;
        const float4 v = *reinterpret_cast<const float4*>(vbase + hw0);
        const float4 a = *reinterpret_cast<const float4*>(
            attn + (size_t)(n * BB + b) * HWN + hw0);
        a0 += a.x * v.x; a1 += a.y * v.y; a2 += a.z * v.z; a3 += a.w * v.w;
    }
    float* optr = out + ((size_t)(b * CC + c)) * HWN + hw0;
    __builtin_nontemporal_store(a0, optr + 0);
    __builtin_nontemporal_store(a1, optr + 1);
    __builtin_nontemporal_store(a2, optr + 2);
    __builtin_nontemporal_store(a3, optr + 3);
}

extern "C" void kernel_launch(void* const* d_in, const int* in_sizes, int n_in,
                              void* d_out, int out_size, void* d_ws, size_t ws_size,
                              hipStream_t stream) {
    const float* blocks = (const float*)d_in[0];
    const float* x      = (const float*)d_in[1];
    const float* w      = (const float*)d_in[2];
    const float* gnw    = (const float*)d_in[3];
    const float* gnb    = (const float*)d_in[4];
    float* out = (float*)d_out;
    float* ws  = (float*)d_ws;

    hipLaunchKernelGGL(k1_stats, dim3(2304), dim3(256), 0, stream, blocks, x, w, gnw, ws);
    hipLaunchKernelGGL(k2_attn, dim3(64), dim3(256), 0, stream, w, gnw, gnb, ws);
    hipLaunchKernelGGL(k3_out, dim3(4096), dim3(256), 0, stream, blocks, x, ws, out);
}